// Round 7
// baseline (20258.200 us; speedup 1.0000x reference)
//
#include <hip/hip_runtime.h>
#include <cstdint>
#include <cstddef>

// Problem constants (fixed by the reference)
#define DD 1024
#define TT 2048
#define NL 4
#define CH 128              // chunk length (timesteps) for pipelined x-GEMV
#define NCH (TT / CH)       // 16 chunks
#define NTHR 1024           // 16 waves per block
#define BPL 64              // blocks per layer (16 cols each)
#define PBLK (NL * BPL)     // 256 blocks = 1 per CU
#define GUARD_LIM (1 << 20) // poll guard; substitute zeros on trip (no hang)

__device__ __forceinline__ float fast_tanh(float x) {
  float e = __expf(2.f * x);
  return 1.f - 2.f / (e + 1.f);
}

// 16B agent-scope load: bypasses the (non-coherent) per-XCD L2.
__device__ __forceinline__ float4 agent_load16(const float* p) {
  float4 r;
  asm volatile("global_load_dwordx4 %0, %1, off sc1\n\t"
               "s_waitcnt vmcnt(0)"
               : "=v"(r) : "v"(p) : "memory");
  return r;
}

// DPP-based wave64 all-reduce add (4 DPP hops + 2 ds_bpermute hops).
template <int CTRL>
__device__ __forceinline__ float dpp_add(float x) {
  int y = __builtin_amdgcn_update_dpp(0, __float_as_int(x), CTRL, 0xf, 0xf, true);
  return x + __int_as_float(y);
}
__device__ __forceinline__ float wave_allreduce_add(float x) {
  x = dpp_add<0xB1>(x);    // quad_perm [1,0,3,2]  : + lane^1
  x = dpp_add<0x4E>(x);    // quad_perm [2,3,0,1]  : + lane^2
  x = dpp_add<0x141>(x);   // row_half_mirror      : + lane^7
  x = dpp_add<0x140>(x);   // row_mirror           : + lane^15
  x += __shfl_xor(x, 16, 64);
  x += __shfl_xor(x, 32, 64);
  return x;
}

__device__ __forceinline__ bool nan_free4(float4 v) {
  unsigned x0 = __float_as_uint(v.x) & 0x7fffffffu;
  unsigned x1 = __float_as_uint(v.y) & 0x7fffffffu;
  unsigned x2 = __float_as_uint(v.z) & 0x7fffffffu;
  unsigned x3 = __float_as_uint(v.w) & 0x7fffffffu;
  return (x0 <= 0x7f800000u) && (x1 <= 0x7f800000u) &&
         (x2 <= 0x7f800000u) && (x3 <= 0x7f800000u);
}

// GEMV x-granule load: plain (L2-cached) fast path; if a NaN sneaks through
// (visibility gap or stale line), fall back to a bounded sc1 spin. Keeps the
// protocol robust without per-granule vmcnt(0) serialization in the common
// case. Legit data is never NaN (h in [-1,1]; X0 bounded).
__device__ __forceinline__ float4 gemv_load16(const float* p, bool check) {
  float4 v = *(const float4*)p;
  if (check && !nan_free4(v)) {
    int tries = 0;
    while (true) {
      v = agent_load16(p);
      if (nan_free4(v)) break;
      if (++tries > 2) __builtin_amdgcn_s_sleep(2);
      if (tries > GUARD_LIM) { v = make_float4(0.f, 0.f, 0.f, 0.f); break; }
    }
  }
  return v;
}

__global__ __launch_bounds__(1024) void prep_kernel(
    const float* __restrict__ sp, const float* __restrict__ rn_p,
    const float* __restrict__ w, const float* __restrict__ b,
    float* __restrict__ X0) {
  int i = blockIdx.x * blockDim.x + threadIdx.x;   // over T*D
  float rn = rn_p[0];
  int c = i & (DD - 1);
  X0[i] = sp[i] + rn * w[c] + b[c];
}

// Persistent pipelined kernel, 1 block per CU. Block b: layer l = b>>6,
// column group grp = b&63 (columns grp*16..grp*16+15). XCD = b&7 = grp&7 =
// rsel, so each replica is read only by the 8 blocks of its own XCD (L2
// locality for the GEMV).
// Per chunk:
//   Gate (l>=1): sc1 NaN-poll of the LAST row of the upstream chunk, then
//     agent-scope ACQUIRE fence (invalidates stale L1/L2 lines).
//   Phase A (GEMV): L2-cached float4 loads with NaN-check + bounded sc1
//     fallback; register-prefetch software pipeline over 64 k-tiles.
//   Phase B (recurrence): 128 steps, ONE barrier each. Wave w owns column
//     col; weights in 16 named float4 VGPRs; DPP allreduce leaves h in all
//     lanes, so lanes 0..R-1 scatter-store all replicas with ONE 4B agent
//     store; waves 0-3 NaN-poll h(t) into the LDS double buffer.
__global__ __launch_bounds__(NTHR, 4) void persist_kernel(
    const float* __restrict__ X0,   // [TT, DD] (valid at launch)
    float* __restrict__ HB,         // [NL*R][TT, DD], NaN-prefilled
    int R,                          // replicas per layer, power of 2, >=1
    const float* __restrict__ Wf1, const float* __restrict__ Wf2,
    const float* __restrict__ Wta, const float* __restrict__ Wtb,
    const float* __restrict__ bf1, const float* __restrict__ bf2,
    const float* __restrict__ bta, const float* __restrict__ btb,
    const float* __restrict__ dt_p,
    float* __restrict__ out_last)   // [DD], written by layer 3 at t=TT-1
{
  __shared__ __align__(16) float hbuf[2][DD];   // 8 KB h double buffer
  __shared__ float zxbuf[CH][64];               // 32 KB per-chunk x-part
  __shared__ float Xs[16][132];                 // 8.4 KB GEMV x tile
  __shared__ float Ws[16][64];                  // 4 KB GEMV weight tile
  __shared__ float lds_pad[7424];               // 29.7 KB: total >80KB => 1 blk/CU

  const int tid = threadIdx.x;
  const int w   = tid >> 6;             // wave 0..15 = column offset
  const int ln  = tid & 63;
  const int l   = blockIdx.x >> 6;      // layer (64 consecutive blocks each)
  const int grp = blockIdx.x & 63;      // column group 0..63
  const int col = grp * 16 + w;
  const float dtv = dt_p[0];

  lds_pad[tid] = (float)tid;            // kept alive by opaque guard below

  const size_t woff = (size_t)l * 2 * DD * DD;

  // ---- h-part weight preload into 16 NAMED float4 regs (64 VGPRs).
  float4 wA0, wA1, wA2, wA3, wB0, wB1, wB2, wB3;
  float4 wC0, wC1, wC2, wC3, wD0, wD1, wD2, wD3;
#define LOADW(dst, base, g) do { \
    const float* p_ = (base) + (size_t)(DD + (g) * 256 + ln * 4) * DD + col; \
    dst = make_float4(p_[0], p_[DD], p_[2 * DD], p_[3 * DD]); \
  } while (0)
  {
    const float* W_ = Wf1 + woff;
    LOADW(wA0, W_, 0); LOADW(wA1, W_, 1); LOADW(wA2, W_, 2); LOADW(wA3, W_, 3);
    W_ = Wf2 + woff;
    LOADW(wB0, W_, 0); LOADW(wB1, W_, 1); LOADW(wB2, W_, 2); LOADW(wB3, W_, 3);
    W_ = Wta + woff;
    LOADW(wC0, W_, 0); LOADW(wC1, W_, 1); LOADW(wC2, W_, 2); LOADW(wC3, W_, 3);
    W_ = Wtb + woff;
    LOADW(wD0, W_, 0); LOADW(wD1, W_, 1); LOADW(wD2, W_, 2); LOADW(wD3, W_, 3);
  }
#undef LOADW

  // ---- GEMV thread mapping: zc = ln (piece p = ln>>4, col ofs ln&15),
  // row-group = w (8 rows each).
  const int p  = ln >> 4;
  const float* Wxp = ((p == 0) ? Wf1 : (p == 1) ? Wf2 : (p == 2) ? Wta : Wtb) + woff;
  const float* bsp = ((p == 0) ? bf1 : (p == 1) ? bf2 : (p == 2) ? bta : btb)
                     + (size_t)l * DD;
  const int colx = grp * 16 + (ln & 15);
  const float biasv = bsp[colx];

  // Replica selection (rsel == own XCD under round-robin dispatch; used
  // only as a locality heuristic — correctness is NaN-check based).
  const int rsel = grp & (R - 1);
  const float* hread = HB + (size_t)(l * R + rsel) * TT * DD;
  const float* xbase = (l == 0) ? X0 : HB + (size_t)((l - 1) * R + rsel) * TT * DD;

  // h_{-1} = 0
  hbuf[0][tid] = 0.f;
  __syncthreads();

#pragma unroll 1
  for (int c = 0; c < NCH; ++c) {
    // ---- Chunk gate (l>=1): wait for last row of upstream chunk, then
    // acquire-fence so plain loads below see the fresh data.
    if (l > 0) {
      if (tid < 256) {
        const float* gsrc = xbase + (size_t)(c * CH + CH - 1) * DD + tid * 4;
        bool ok = false;
        int tries = 0;
        while (true) {
          if (!ok) ok = nan_free4(agent_load16(gsrc));
          if (__all(ok)) break;
          if (++tries > 2) __builtin_amdgcn_s_sleep(8);
          if (tries > GUARD_LIM) break;   // degrade, don't hang
        }
      }
      __syncthreads();
      __builtin_amdgcn_fence(__ATOMIC_ACQUIRE, "agent");
    }

    // ========== Phase A: chunk x-GEMV (L2 loads + NaN fallback) ==========
    float acc[8];
#pragma unroll
    for (int i = 0; i < 8; ++i) acc[i] = 0.f;

    const int xrow = tid >> 2;            // 0..127 (waves 0-7)
    const int xq   = (tid & 3) * 4;       // k-quad
    const float* xrowp = xbase + (size_t)(c * CH + xrow) * DD + xq;
    const bool chk = (l > 0);

    float4 xv = make_float4(0.f, 0.f, 0.f, 0.f);
    if (tid < 512) xv = gemv_load16(xrowp, chk);
    float wv = Wxp[(size_t)w * DD + colx];

#pragma unroll 1
    for (int k0 = 0; k0 < DD; k0 += 16) {
      // Write current tile to LDS from regs.
      if (tid < 512) {
        Xs[xq + 0][xrow] = xv.x; Xs[xq + 1][xrow] = xv.y;
        Xs[xq + 2][xrow] = xv.z; Xs[xq + 3][xrow] = xv.w;
      }
      Ws[w][ln] = wv;
      __syncthreads();
      // Prefetch next tile (hides L2 latency under the FMAs).
      if (k0 + 16 < DD) {
        if (tid < 512) xv = gemv_load16(xrowp + k0 + 16, chk);
        wv = Wxp[(size_t)(k0 + 16 + w) * DD + colx];
      }
#pragma unroll
      for (int kk = 0; kk < 16; ++kk) {
        float wvk = Ws[kk][ln];
        float4 x0 = *(const float4*)&Xs[kk][w * 8];       // broadcast per wave
        float4 x1 = *(const float4*)&Xs[kk][w * 8 + 4];
        acc[0] = fmaf(x0.x, wvk, acc[0]); acc[1] = fmaf(x0.y, wvk, acc[1]);
        acc[2] = fmaf(x0.z, wvk, acc[2]); acc[3] = fmaf(x0.w, wvk, acc[3]);
        acc[4] = fmaf(x1.x, wvk, acc[4]); acc[5] = fmaf(x1.y, wvk, acc[5]);
        acc[6] = fmaf(x1.z, wvk, acc[6]); acc[7] = fmaf(x1.w, wvk, acc[7]);
      }
      __syncthreads();
    }
#pragma unroll
    for (int i = 0; i < 8; ++i) zxbuf[w * 8 + i][ln] = acc[i] + biasv;
    __syncthreads();

    // ========== Phase B: recurrence over the chunk (1 barrier/step) ========
#pragma unroll 1
    for (int tl = 0; tl < CH; ++tl) {
      const int t = c * CH + tl;
      const float* rbuf = hbuf[t & 1];

      // x-part: lane ln<4 holds piece ln's zx value for column w.
      float zxv = (ln < 4) ? zxbuf[tl][ln * 16 + w] : 0.f;
      float a0 = (ln == 0) ? zxv : 0.f;
      float a1 = (ln == 1) ? zxv : 0.f;
      float a2 = (ln == 2) ? zxv : 0.f;
      float a3 = (ln == 3) ? zxv : 0.f;

#define DOTG(g, WA, WB, WC, WD) do { \
      float4 h4 = *(const float4*)&rbuf[(g) * 256 + ln * 4]; \
      a0 = fmaf(h4.x, WA.x, a0); a0 = fmaf(h4.y, WA.y, a0); \
      a0 = fmaf(h4.z, WA.z, a0); a0 = fmaf(h4.w, WA.w, a0); \
      a1 = fmaf(h4.x, WB.x, a1); a1 = fmaf(h4.y, WB.y, a1); \
      a1 = fmaf(h4.z, WB.z, a1); a1 = fmaf(h4.w, WB.w, a1); \
      a2 = fmaf(h4.x, WC.x, a2); a2 = fmaf(h4.y, WC.y, a2); \
      a2 = fmaf(h4.z, WC.z, a2); a2 = fmaf(h4.w, WC.w, a2); \
      a3 = fmaf(h4.x, WD.x, a3); a3 = fmaf(h4.y, WD.y, a3); \
      a3 = fmaf(h4.z, WD.z, a3); a3 = fmaf(h4.w, WD.w, a3); \
    } while (0)
      DOTG(0, wA0, wB0, wC0, wD0);
      DOTG(1, wA1, wB1, wC1, wD1);
      DOTG(2, wA2, wB2, wC2, wD2);
      DOTG(3, wA3, wB3, wC3, wD3);
#undef DOTG

      a0 = wave_allreduce_add(a0);
      a1 = wave_allreduce_add(a1);
      a2 = wave_allreduce_add(a2);
      a3 = wave_allreduce_add(a3);

      float f1 = fast_tanh(a0);
      float f2 = fast_tanh(a1);
      float g  = 1.f / (1.f + __expf(a2 * dtv - a3));
      float h  = fmaf(g, f1 - f2, f2);   // every lane holds h for column col

      // Publish immediately: lanes 0..R-1 scatter-store all replicas in
      // ONE 4B agent store instruction per wave.
      if (ln < R) {
        __hip_atomic_store(
            &HB[(size_t)(l * R + ln) * TT * DD + (size_t)t * DD + col], h,
            __ATOMIC_RELAXED, __HIP_MEMORY_SCOPE_AGENT);
      }
      if (l == 3 && t == TT - 1 && ln == 0 && out_last) out_last[col] = h;

      // Poll h(t): waves 0-3 (16B per thread, early-out, backoff) into the
      // other buffer; waves 4-15 go straight to the barrier.
      if (t < TT - 1 && tid < 256) {
        const float* src = &hread[(size_t)t * DD + tid * 4];
        float4 v = make_float4(0.f, 0.f, 0.f, 0.f);
        bool ok = false;
        int tries = 0;
        while (true) {
          if (!ok) {
            v = agent_load16(src);
            ok = nan_free4(v);
          }
          if (__all(ok)) break;
          if (++tries > 8) __builtin_amdgcn_s_sleep(1);
          if (tries > GUARD_LIM) break;
        }
        if (!ok) v = make_float4(0.f, 0.f, 0.f, 0.f);   // degrade, don't hang
        *(float4*)&hbuf[(t + 1) & 1][tid * 4] = v;
      }
      __syncthreads();
    }
  }

  // Opaque guard: out_last's value is unknown at compile time, so the pad
  // array (and its store) cannot be dead-code-eliminated. Never true.
  if ((uintptr_t)out_last == 1) out_last[0] = lds_pad[tid];
}

extern "C" void kernel_launch(void* const* d_in, const int* in_sizes, int n_in,
                              void* d_out, int out_size, void* d_ws, size_t ws_size,
                              hipStream_t stream) {
  const float* sp  = (const float*)d_in[0];
  const float* rn  = (const float*)d_in[1];
  const float* dt  = (const float*)d_in[2];
  const float* rw  = (const float*)d_in[3];
  const float* rb  = (const float*)d_in[4];
  const float* Wf1 = (const float*)d_in[5];
  const float* bf1 = (const float*)d_in[6];
  const float* Wf2 = (const float*)d_in[7];
  const float* bf2 = (const float*)d_in[8];
  const float* Wta = (const float*)d_in[9];
  const float* bta = (const float*)d_in[10];
  const float* Wtb = (const float*)d_in[11];
  const float* btb = (const float*)d_in[12];

  float* ws = (float*)d_ws;
  float* X0 = ws;                         // [TT, DD]
  float* HB = ws + (size_t)TT * DD;       // [NL*R][TT, DD]
  float* out = (float*)d_out;

  // Adaptive replica count (power of 2, max 8), limited by workspace size.
  int R = 1;
  for (int cand = 8; cand >= 1; cand >>= 1) {
    size_t need = sizeof(float) * (size_t)TT * DD * (size_t)(1 + NL * cand);
    if (need <= ws_size) { R = cand; break; }
  }

  // NaN-prefill all h buffers (poll protocol), then launch.
  (void)hipMemsetAsync(HB, 0xFF, sizeof(float) * (size_t)NL * R * TT * DD, stream);
  prep_kernel<<<(TT * DD) / 1024, 1024, 0, stream>>>(sp, rn, rw, rb, X0);
  persist_kernel<<<PBLK, NTHR, 0, stream>>>(X0, HB, R, Wf1, Wf2, Wta, Wtb,
      bf1, bf2, bta, btb, dt, out);
}

// Round 9
// 11012.211 us; speedup vs baseline: 1.8396x; 1.8396x over previous
//
#include <hip/hip_runtime.h>
#include <cstdint>
#include <cstddef>

// Problem constants (fixed by the reference)
#define DD 1024
#define TT 2048
#define NL 4
#define CH 64               // chunk length (timesteps) for pipelined x-GEMV
#define NCH (TT / CH)       // 32 chunks
#define NTHR 1024           // 16 waves per block
#define BPL 64              // blocks per layer (16 cols each)
#define PBLK (NL * BPL)     // 256 blocks = 1 per CU (LDS-forced)
#define GUARD_LIM (1 << 20) // poll guard; substitute zeros on trip (no hang)

__device__ __forceinline__ float fast_tanh(float x) {
  float e = __expf(2.f * x);
  return 1.f - 2.f / (e + 1.f);
}

// 16B agent-scope load (blocking): bypasses the per-XCD L2.
__device__ __forceinline__ float4 agent_load16(const float* p) {
  float4 r;
  asm volatile("global_load_dwordx4 %0, %1, off sc1\n\t"
               "s_waitcnt vmcnt(0)"
               : "=v"(r) : "v"(p) : "memory");
  return r;
}
// 4B agent-scope load (blocking): for flag polls.
__device__ __forceinline__ unsigned agent_load4(const unsigned* p) {
  unsigned r;
  asm volatile("global_load_dword %0, %1, off sc1\n\t"
               "s_waitcnt vmcnt(0)"
               : "=v"(r) : "v"(p) : "memory");
  return r;
}
// 16B agent-scope store as two 8B atomic stores (4B-granule atomicity is all
// the NaN-poll protocol needs; half-visible granule still has NaN words).
__device__ __forceinline__ void agent_store16(float* p, float4 v) {
  unsigned long long lo =
      ((unsigned long long)__float_as_uint(v.y) << 32) | __float_as_uint(v.x);
  unsigned long long hi =
      ((unsigned long long)__float_as_uint(v.w) << 32) | __float_as_uint(v.z);
  __hip_atomic_store((unsigned long long*)p, lo,
                     __ATOMIC_RELAXED, __HIP_MEMORY_SCOPE_AGENT);
  __hip_atomic_store(((unsigned long long*)p) + 1, hi,
                     __ATOMIC_RELAXED, __HIP_MEMORY_SCOPE_AGENT);
}

// DPP-based wave64 all-reduce add (4 DPP hops + 2 ds_bpermute hops).
template <int CTRL>
__device__ __forceinline__ float dpp_add(float x) {
  int y = __builtin_amdgcn_update_dpp(0, __float_as_int(x), CTRL, 0xf, 0xf, true);
  return x + __int_as_float(y);
}
__device__ __forceinline__ float wave_allreduce_add(float x) {
  x = dpp_add<0xB1>(x);    // quad_perm [1,0,3,2]  : + lane^1
  x = dpp_add<0x4E>(x);    // quad_perm [2,3,0,1]  : + lane^2
  x = dpp_add<0x141>(x);   // row_half_mirror      : + lane^7
  x = dpp_add<0x140>(x);   // row_mirror           : + lane^15
  x += __shfl_xor(x, 16, 64);
  x += __shfl_xor(x, 32, 64);
  return x;
}

__device__ __forceinline__ bool nan_free4(float4 v) {
  unsigned x0 = __float_as_uint(v.x) & 0x7fffffffu;
  unsigned x1 = __float_as_uint(v.y) & 0x7fffffffu;
  unsigned x2 = __float_as_uint(v.z) & 0x7fffffffu;
  unsigned x3 = __float_as_uint(v.w) & 0x7fffffffu;
  return (x0 <= 0x7f800000u) && (x1 <= 0x7f800000u) &&
         (x2 <= 0x7f800000u) && (x3 <= 0x7f800000u);
}

__global__ __launch_bounds__(1024) void prep_kernel(
    const float* __restrict__ sp, const float* __restrict__ rn_p,
    const float* __restrict__ w, const float* __restrict__ b,
    float* __restrict__ X0) {
  int i = blockIdx.x * blockDim.x + threadIdx.x;   // over T*D
  float rn = rn_p[0];
  int c = i & (DD - 1);
  X0[i] = sp[i] + rn * w[c] + b[c];
}

// Persistent pipelined kernel, 1 block per CU (LDS >80KB forces single
// residency). Block b: layer l = b>>6, column group grp = b&63 (columns
// grp*16..grp*16+15). XCD = b&7 = grp&7 = rsel.
// Per chunk:
//   Gate (l>=1): sc1 NaN-poll of the LAST row of the upstream chunk
//     (producers write rows in order; last-row => chunk complete).
//   Phase A (GEMV): 64-k super-tiles; all 1024 threads load one 16B sc1
//     granule each (one blocking RT per super-tile, 16 per chunk).
//   Phase B (recurrence): DOTG from LDS broadcast, DPP allreduce, gate
//     math, hq gather (barrier), wave 0 publishes 64B data + 4B FLAG per
//     replica; readers (waves 0-3) spin on the 64 producer FLAGS (1KB/rnd
//     vs 4KB data polls), then bulk-read h once with NaN-respin fallback.
__global__ __launch_bounds__(NTHR, 4) void persist_kernel(
    const float* __restrict__ X0,   // [TT, DD] (valid at launch)
    float* __restrict__ HB,         // [NL*R][TT, DD], NaN-prefilled
    unsigned* __restrict__ FLG,     // [NL*R][TT][64], 0xFF-prefilled
    int R,                          // replicas per layer, power of 2, >=1
    const float* __restrict__ Wf1, const float* __restrict__ Wf2,
    const float* __restrict__ Wta, const float* __restrict__ Wtb,
    const float* __restrict__ bf1, const float* __restrict__ bf2,
    const float* __restrict__ bta, const float* __restrict__ btb,
    const float* __restrict__ dt_p,
    float* __restrict__ out_last)   // [DD], written by layer 3 at t=TT-1
{
  __shared__ __align__(16) float hbuf[2][DD];   // 8 KB h double buffer
  __shared__ float zxbuf[CH][64];               // 16 KB per-chunk x-part
  __shared__ float Xs[64][68];                  // 17.4 KB GEMV x super-tile
  __shared__ float Ws[64][64];                  // 16 KB GEMV weight tile
  __shared__ __align__(64) float hq[16];        // h gather across waves
  __shared__ float lds_pad[6144];               // 24 KB: total >80KB => 1 blk/CU

  const int tid = threadIdx.x;
  const int w   = tid >> 6;             // wave 0..15 = column offset
  const int ln  = tid & 63;
  const int l   = blockIdx.x >> 6;      // layer (64 consecutive blocks each)
  const int grp = blockIdx.x & 63;      // column group 0..63
  const int col = grp * 16 + w;
  const float dtv = dt_p[0];

  if (tid < 6144) lds_pad[tid] = (float)tid;  // kept alive by guard below

  const size_t woff = (size_t)l * 2 * DD * DD;

  // ---- h-part weight preload into 16 NAMED float4 regs (64 VGPRs).
  float4 wA0, wA1, wA2, wA3, wB0, wB1, wB2, wB3;
  float4 wC0, wC1, wC2, wC3, wD0, wD1, wD2, wD3;
#define LOADW(dst, base, g) do { \
    const float* p_ = (base) + (size_t)(DD + (g) * 256 + ln * 4) * DD + col; \
    dst = make_float4(p_[0], p_[DD], p_[2 * DD], p_[3 * DD]); \
  } while (0)
  {
    const float* W_ = Wf1 + woff;
    LOADW(wA0, W_, 0); LOADW(wA1, W_, 1); LOADW(wA2, W_, 2); LOADW(wA3, W_, 3);
    W_ = Wf2 + woff;
    LOADW(wB0, W_, 0); LOADW(wB1, W_, 1); LOADW(wB2, W_, 2); LOADW(wB3, W_, 3);
    W_ = Wta + woff;
    LOADW(wC0, W_, 0); LOADW(wC1, W_, 1); LOADW(wC2, W_, 2); LOADW(wC3, W_, 3);
    W_ = Wtb + woff;
    LOADW(wD0, W_, 0); LOADW(wD1, W_, 1); LOADW(wD2, W_, 2); LOADW(wD3, W_, 3);
  }
#undef LOADW

  // ---- GEMV thread mapping: z-col = ln (piece p = ln>>4, col ofs ln&15).
  const int p  = ln >> 4;
  const float* Wxp = ((p == 0) ? Wf1 : (p == 1) ? Wf2 : (p == 2) ? Wta : Wtb) + woff;
  const float* bsp = ((p == 0) ? bf1 : (p == 1) ? bf2 : (p == 2) ? bta : btb)
                     + (size_t)l * DD;
  const int colx = grp * 16 + (ln & 15);
  const float biasv = bsp[colx];

  // Replica selection (rsel == own XCD under round-robin dispatch).
  const int rsel = grp & (R - 1);
  const float* hread = HB + (size_t)(l * R + rsel) * TT * DD;
  const unsigned* FLGr = FLG + (size_t)(l * R + rsel) * TT * 64;
  const float* xbase = (l == 0) ? X0 : HB + (size_t)((l - 1) * R + rsel) * TT * DD;

  // h_{-1} = 0
  hbuf[0][tid] = 0.f;
  __syncthreads();

#pragma unroll 1
  for (int c = 0; c < NCH; ++c) {
    // ---- Chunk gate (l>=1): wait for last row of upstream chunk (R5 form).
    if (l > 0) {
      if (tid < 256) {
        const float* gsrc = xbase + (size_t)(c * CH + CH - 1) * DD + tid * 4;
        bool ok = false;
        int tries = 0;
        while (true) {
          if (!ok) ok = nan_free4(agent_load16(gsrc));
          if (__all(ok)) break;
          if (++tries > 2) __builtin_amdgcn_s_sleep(8);
          if (tries > GUARD_LIM) break;   // degrade, don't hang
        }
      }
      __syncthreads();
    }

    // ====== Phase A: chunk x-GEMV (64-k super-tiles, 1 RT each) ======
    float acc[4];
#pragma unroll
    for (int i = 0; i < 4; ++i) acc[i] = 0.f;

    const int xrow = tid >> 4;            // 0..63 (all 16 waves load)
    const int xq   = (tid & 15) * 4;      // k-offset within super-tile
    const float* xrowp = xbase + (size_t)(c * CH + xrow) * DD + xq;

#pragma unroll 1
    for (int k0 = 0; k0 < DD; k0 += 64) {
      // X super-tile [64k][64t] (transposed): one granule per thread.
      {
        const float* src = xrowp + k0;
        float4 v = (l == 0) ? *(const float4*)src : agent_load16(src);
        Xs[xq + 0][xrow] = v.x; Xs[xq + 1][xrow] = v.y;
        Xs[xq + 2][xrow] = v.z; Xs[xq + 3][xrow] = v.w;
      }
      // Weight tile [64k][64z]: 4 plain loads per thread.
#pragma unroll
      for (int j = 0; j < 4; ++j)
        Ws[w * 4 + j][ln] = Wxp[(size_t)(k0 + w * 4 + j) * DD + colx];
      __syncthreads();
#pragma unroll 16
      for (int kk = 0; kk < 64; ++kk) {
        float wvk = Ws[kk][ln];
        float4 x = *(const float4*)&Xs[kk][w * 4];   // wave-broadcast read
        acc[0] = fmaf(x.x, wvk, acc[0]); acc[1] = fmaf(x.y, wvk, acc[1]);
        acc[2] = fmaf(x.z, wvk, acc[2]); acc[3] = fmaf(x.w, wvk, acc[3]);
      }
      __syncthreads();
    }
#pragma unroll
    for (int i = 0; i < 4; ++i) zxbuf[w * 4 + i][ln] = acc[i] + biasv;
    __syncthreads();

    // ========== Phase B: recurrence over the chunk (R5 structure) ==========
#pragma unroll 1
    for (int tl = 0; tl < CH; ++tl) {
      const int t = c * CH + tl;
      const float* rbuf = hbuf[t & 1];

      // x-part: lane ln<4 holds piece ln's zx value for column w.
      float zxv = (ln < 4) ? zxbuf[tl][ln * 16 + w] : 0.f;
      float a0 = (ln == 0) ? zxv : 0.f;
      float a1 = (ln == 1) ? zxv : 0.f;
      float a2 = (ln == 2) ? zxv : 0.f;
      float a3 = (ln == 3) ? zxv : 0.f;

#define DOTG(g, WA, WB, WC, WD) do { \
      float4 h4 = *(const float4*)&rbuf[(g) * 256 + ln * 4]; \
      a0 = fmaf(h4.x, WA.x, a0); a0 = fmaf(h4.y, WA.y, a0); \
      a0 = fmaf(h4.z, WA.z, a0); a0 = fmaf(h4.w, WA.w, a0); \
      a1 = fmaf(h4.x, WB.x, a1); a1 = fmaf(h4.y, WB.y, a1); \
      a1 = fmaf(h4.z, WB.z, a1); a1 = fmaf(h4.w, WB.w, a1); \
      a2 = fmaf(h4.x, WC.x, a2); a2 = fmaf(h4.y, WC.y, a2); \
      a2 = fmaf(h4.z, WC.z, a2); a2 = fmaf(h4.w, WC.w, a2); \
      a3 = fmaf(h4.x, WD.x, a3); a3 = fmaf(h4.y, WD.y, a3); \
      a3 = fmaf(h4.z, WD.z, a3); a3 = fmaf(h4.w, WD.w, a3); \
    } while (0)
      DOTG(0, wA0, wB0, wC0, wD0);
      DOTG(1, wA1, wB1, wC1, wD1);
      DOTG(2, wA2, wB2, wC2, wD2);
      DOTG(3, wA3, wB3, wC3, wD3);
#undef DOTG

      a0 = wave_allreduce_add(a0);
      a1 = wave_allreduce_add(a1);
      a2 = wave_allreduce_add(a2);
      a3 = wave_allreduce_add(a3);

      float f1 = fast_tanh(a0);
      float f2 = fast_tanh(a1);
      float g  = 1.f / (1.f + __expf(a2 * dtv - a3));
      float h  = fmaf(g, f1 - f2, f2);

      if (ln == 0) hq[w] = h;
      if (l == 3 && t == TT - 1 && ln == 0 && out_last) out_last[col] = h;
      __syncthreads();   // hq ready

      // Publish: wave 0, lanes 0..R-1: 64B data message + 4B flag (value=t)
      // per replica. No fence between — readers NaN-check data anyway.
      if (w == 0 && ln < R) {
        float* dst = HB + (size_t)(l * R + ln) * TT * DD + (size_t)t * DD + grp * 16;
        float4 q0 = *(const float4*)&hq[0];
        float4 q1 = *(const float4*)&hq[4];
        float4 q2 = *(const float4*)&hq[8];
        float4 q3 = *(const float4*)&hq[12];
        agent_store16(dst + 0,  q0);
        agent_store16(dst + 4,  q1);
        agent_store16(dst + 8,  q2);
        agent_store16(dst + 12, q3);
        __hip_atomic_store(&FLG[((size_t)(l * R + ln) * TT + t) * 64 + grp],
                           (unsigned)t, __ATOMIC_RELAXED,
                           __HIP_MEMORY_SCOPE_AGENT);
      }

      // Readers: waves 0-3. Spin on the 64 producer flags (4B/lane/round),
      // then bulk-read the h row once with per-granule NaN-respin fallback.
      if (t < TT - 1 && tid < 256) {
        const unsigned* fp = FLGr + (size_t)t * 64 + ln;
        bool fok = false;
        int tries = 0;
        while (true) {
          if (!fok) fok = (agent_load4(fp) == (unsigned)t);
          if (__all(fok)) break;
          if (++tries > 8) __builtin_amdgcn_s_sleep(1);
          if (tries > GUARD_LIM) break;
        }
        const float* src = &hread[(size_t)t * DD + tid * 4];
        float4 v = agent_load16(src);
        int g2 = 0;
        while (!nan_free4(v)) {          // flag overtook data: rare respin
          if (++g2 > GUARD_LIM) { v = make_float4(0.f, 0.f, 0.f, 0.f); break; }
          if (g2 > 4) __builtin_amdgcn_s_sleep(1);
          v = agent_load16(src);
        }
        *(float4*)&hbuf[(t + 1) & 1][tid * 4] = v;
      }
      __syncthreads();
    }
  }

  // Opaque guard: keeps lds_pad (and its store) from being DCE'd. Never true.
  if ((uintptr_t)out_last == 1) out_last[0] = lds_pad[tid & 1023];
}

extern "C" void kernel_launch(void* const* d_in, const int* in_sizes, int n_in,
                              void* d_out, int out_size, void* d_ws, size_t ws_size,
                              hipStream_t stream) {
  const float* sp  = (const float*)d_in[0];
  const float* rn  = (const float*)d_in[1];
  const float* dt  = (const float*)d_in[2];
  const float* rw  = (const float*)d_in[3];
  const float* rb  = (const float*)d_in[4];
  const float* Wf1 = (const float*)d_in[5];
  const float* bf1 = (const float*)d_in[6];
  const float* Wf2 = (const float*)d_in[7];
  const float* bf2 = (const float*)d_in[8];
  const float* Wta = (const float*)d_in[9];
  const float* bta = (const float*)d_in[10];
  const float* Wtb = (const float*)d_in[11];
  const float* btb = (const float*)d_in[12];

  float* ws = (float*)d_ws;
  float* X0 = ws;                         // [TT, DD]
  float* HB = ws + (size_t)TT * DD;       // [NL*R][TT, DD]
  float* out = (float*)d_out;
  const size_t seqB = sizeof(float) * (size_t)TT * DD;      // 8 MB
  const size_t flgPerRep = (size_t)TT * 64 * sizeof(unsigned);  // 512 KB

  // Adaptive replica count (power of 2, max 8), limited by workspace size.
  int R = 1;
  for (int cand = 8; cand >= 1; cand >>= 1) {
    size_t need = seqB + (size_t)NL * cand * (seqB + flgPerRep);
    if (need <= ws_size) { R = cand; break; }
  }
  // FLG sits directly after HB so one memset poisons both.
  unsigned* FLG = (unsigned*)(ws + (size_t)(1 + NL * R) * TT * DD);

  // NaN/0xFF-prefill h buffers + flags (poll protocol), then launch.
  (void)hipMemsetAsync(HB, 0xFF, (size_t)NL * R * (seqB + flgPerRep), stream);
  prep_kernel<<<(TT * DD) / 1024, 1024, 0, stream>>>(sp, rn, rw, rb, X0);
  persist_kernel<<<PBLK, NTHR, 0, stream>>>(X0, HB, FLG, R, Wf1, Wf2, Wta, Wtb,
      bf1, bf2, bta, btb, dt, out);
}

// Round 10
// 10360.879 us; speedup vs baseline: 1.9553x; 1.0629x over previous
//
#include <hip/hip_runtime.h>
#include <cstdint>
#include <cstddef>

// Problem constants (fixed by the reference)
#define DD 1024
#define TT 2048
#define NL 4
#define CH 64               // chunk length (timesteps) for pipelined x-GEMV
#define NCH (TT / CH)       // 32 chunks
#define NTHR 1024           // 16 waves per block
#define BPL 64              // blocks per layer (16 cols each)
#define PBLK (NL * BPL)     // 256 blocks = 1 per CU (LDS-forced)
#define GUARD_LIM (1 << 20) // poll guard; substitute zeros on trip (no hang)

__device__ __forceinline__ float fast_tanh(float x) {
  float e = __expf(2.f * x);
  return 1.f - 2.f / (e + 1.f);
}

// 16B agent-scope load (blocking): bypasses the per-XCD L2.
__device__ __forceinline__ float4 agent_load16(const float* p) {
  float4 r;
  asm volatile("global_load_dwordx4 %0, %1, off sc1\n\t"
               "s_waitcnt vmcnt(0)"
               : "=v"(r) : "v"(p) : "memory");
  return r;
}
// 16B agent-scope store as two 8B atomic stores (4B-granule atomicity is all
// the NaN-poll protocol needs; half-visible granule still has NaN words).
__device__ __forceinline__ void agent_store16(float* p, float4 v) {
  unsigned long long lo =
      ((unsigned long long)__float_as_uint(v.y) << 32) | __float_as_uint(v.x);
  unsigned long long hi =
      ((unsigned long long)__float_as_uint(v.w) << 32) | __float_as_uint(v.z);
  __hip_atomic_store((unsigned long long*)p, lo,
                     __ATOMIC_RELAXED, __HIP_MEMORY_SCOPE_AGENT);
  __hip_atomic_store(((unsigned long long*)p) + 1, hi,
                     __ATOMIC_RELAXED, __HIP_MEMORY_SCOPE_AGENT);
}

// DPP-based wave64 all-reduce add (4 DPP hops + 2 ds_bpermute hops).
template <int CTRL>
__device__ __forceinline__ float dpp_add(float x) {
  int y = __builtin_amdgcn_update_dpp(0, __float_as_int(x), CTRL, 0xf, 0xf, true);
  return x + __int_as_float(y);
}
__device__ __forceinline__ float wave_allreduce_add(float x) {
  x = dpp_add<0xB1>(x);    // quad_perm [1,0,3,2]  : + lane^1
  x = dpp_add<0x4E>(x);    // quad_perm [2,3,0,1]  : + lane^2
  x = dpp_add<0x141>(x);   // row_half_mirror      : + lane^7
  x = dpp_add<0x140>(x);   // row_mirror           : + lane^15
  x += __shfl_xor(x, 16, 64);
  x += __shfl_xor(x, 32, 64);
  return x;
}

__device__ __forceinline__ bool nan_free4(float4 v) {
  unsigned x0 = __float_as_uint(v.x) & 0x7fffffffu;
  unsigned x1 = __float_as_uint(v.y) & 0x7fffffffu;
  unsigned x2 = __float_as_uint(v.z) & 0x7fffffffu;
  unsigned x3 = __float_as_uint(v.w) & 0x7fffffffu;
  return (x0 <= 0x7f800000u) && (x1 <= 0x7f800000u) &&
         (x2 <= 0x7f800000u) && (x3 <= 0x7f800000u);
}

__global__ __launch_bounds__(1024) void prep_kernel(
    const float* __restrict__ sp, const float* __restrict__ rn_p,
    const float* __restrict__ w, const float* __restrict__ b,
    float* __restrict__ X0) {
  int i = blockIdx.x * blockDim.x + threadIdx.x;   // over T*D
  float rn = rn_p[0];
  int c = i & (DD - 1);
  X0[i] = sp[i] + rn * w[c] + b[c];
}

// Persistent pipelined kernel, 1 block per CU (LDS >80KB forces single
// residency). Block b: layer l = b>>6, column group grp = b&63 (columns
// grp*16..grp*16+15).
// Per chunk:
//   Gate (l>=1): sc1 NaN-poll of the LAST row of the upstream chunk.
//   Phase A (GEMV): 64-k super-tiles; all 1024 threads load one 16B sc1
//     granule each (one blocking RT per super-tile, 16 per chunk).
//   Phase B (recurrence), ONE barrier per step:
//     - per-group arrival overlap: poll-wave w fills h-group w (256 floats)
//       of hbuf[(t+1)&1] and release-stores ready[w]=t; compute spins on
//       ready[g] immediately before DOTG(g) — early groups' FMAs overlap
//       late groups' fabric arrival.
//     - barrier-free publish: each wave deposits h into hq + release-adds
//       hcnt; wave 15 spins for 16 deposits then fires R x 64B sc1 stores.
__global__ __launch_bounds__(NTHR, 4) void persist_kernel(
    const float* __restrict__ X0,   // [TT, DD] (valid at launch)
    float* __restrict__ HB,         // [NL*R][TT, DD], NaN-prefilled
    int R,                          // replicas per layer, power of 2, >=1
    const float* __restrict__ Wf1, const float* __restrict__ Wf2,
    const float* __restrict__ Wta, const float* __restrict__ Wtb,
    const float* __restrict__ bf1, const float* __restrict__ bf2,
    const float* __restrict__ bta, const float* __restrict__ btb,
    const float* __restrict__ dt_p,
    float* __restrict__ out_last)   // [DD], written by layer 3 at t=TT-1
{
  __shared__ __align__(16) float hbuf[2][DD];   // 8 KB h double buffer
  __shared__ float zxbuf[CH][64];               // 16 KB per-chunk x-part
  __shared__ float Xs[64][68];                  // 17.4 KB GEMV x super-tile
  __shared__ float Ws[64][64];                  // 16 KB GEMV weight tile
  __shared__ __align__(64) float hq[16];        // h gather across waves
  __shared__ int ready[4];                      // per-group arrival flags
  __shared__ int hcnt;                          // deposit counter
  __shared__ float lds_pad[6144];               // 24 KB: total >80KB => 1/CU

  const int tid = threadIdx.x;
  const int w   = tid >> 6;             // wave 0..15 = column offset
  const int ln  = tid & 63;
  const int l   = blockIdx.x >> 6;      // layer (64 consecutive blocks each)
  const int grp = blockIdx.x & 63;      // column group 0..63
  const int col = grp * 16 + w;
  const float dtv = dt_p[0];

  if (tid < 6144) lds_pad[tid] = (float)tid;  // kept alive by guard below
  if (tid == 0) {
    hcnt = 0;
    ready[0] = ready[1] = ready[2] = ready[3] = -1;
  }

  const size_t woff = (size_t)l * 2 * DD * DD;

  // ---- h-part weight preload into 16 NAMED float4 regs (64 VGPRs).
  float4 wA0, wA1, wA2, wA3, wB0, wB1, wB2, wB3;
  float4 wC0, wC1, wC2, wC3, wD0, wD1, wD2, wD3;
#define LOADW(dst, base, g) do { \
    const float* p_ = (base) + (size_t)(DD + (g) * 256 + ln * 4) * DD + col; \
    dst = make_float4(p_[0], p_[DD], p_[2 * DD], p_[3 * DD]); \
  } while (0)
  {
    const float* W_ = Wf1 + woff;
    LOADW(wA0, W_, 0); LOADW(wA1, W_, 1); LOADW(wA2, W_, 2); LOADW(wA3, W_, 3);
    W_ = Wf2 + woff;
    LOADW(wB0, W_, 0); LOADW(wB1, W_, 1); LOADW(wB2, W_, 2); LOADW(wB3, W_, 3);
    W_ = Wta + woff;
    LOADW(wC0, W_, 0); LOADW(wC1, W_, 1); LOADW(wC2, W_, 2); LOADW(wC3, W_, 3);
    W_ = Wtb + woff;
    LOADW(wD0, W_, 0); LOADW(wD1, W_, 1); LOADW(wD2, W_, 2); LOADW(wD3, W_, 3);
  }
#undef LOADW

  // ---- GEMV thread mapping: z-col = ln (piece p = ln>>4, col ofs ln&15).
  const int p  = ln >> 4;
  const float* Wxp = ((p == 0) ? Wf1 : (p == 1) ? Wf2 : (p == 2) ? Wta : Wtb) + woff;
  const float* bsp = ((p == 0) ? bf1 : (p == 1) ? bf2 : (p == 2) ? bta : btb)
                     + (size_t)l * DD;
  const int colx = grp * 16 + (ln & 15);
  const float biasv = bsp[colx];

  // Replica selection (rsel == own XCD under round-robin dispatch).
  const int rsel = grp & (R - 1);
  const float* hread = HB + (size_t)(l * R + rsel) * TT * DD;
  const float* xbase = (l == 0) ? X0 : HB + (size_t)((l - 1) * R + rsel) * TT * DD;

  // h_{-1} = 0
  hbuf[0][tid] = 0.f;
  __syncthreads();

#pragma unroll 1
  for (int c = 0; c < NCH; ++c) {
    // ---- Chunk gate (l>=1): wait for last row of upstream chunk (R5 form).
    if (l > 0) {
      if (tid < 256) {
        const float* gsrc = xbase + (size_t)(c * CH + CH - 1) * DD + tid * 4;
        bool ok = false;
        int tries = 0;
        while (true) {
          if (!ok) ok = nan_free4(agent_load16(gsrc));
          if (__all(ok)) break;
          if (++tries > 2) __builtin_amdgcn_s_sleep(8);
          if (tries > GUARD_LIM) break;   // degrade, don't hang
        }
      }
      __syncthreads();
    }

    // ====== Phase A: chunk x-GEMV (64-k super-tiles, 1 RT each) ======
    float acc[4];
#pragma unroll
    for (int i = 0; i < 4; ++i) acc[i] = 0.f;

    const int xrow = tid >> 4;            // 0..63 (all 16 waves load)
    const int xq   = (tid & 15) * 4;      // k-offset within super-tile
    const float* xrowp = xbase + (size_t)(c * CH + xrow) * DD + xq;

#pragma unroll 1
    for (int k0 = 0; k0 < DD; k0 += 64) {
      // X super-tile [64k][64t] (transposed): one granule per thread.
      {
        const float* src = xrowp + k0;
        float4 v = (l == 0) ? *(const float4*)src : agent_load16(src);
        Xs[xq + 0][xrow] = v.x; Xs[xq + 1][xrow] = v.y;
        Xs[xq + 2][xrow] = v.z; Xs[xq + 3][xrow] = v.w;
      }
      // Weight tile [64k][64z]: 4 plain loads per thread.
#pragma unroll
      for (int j = 0; j < 4; ++j)
        Ws[w * 4 + j][ln] = Wxp[(size_t)(k0 + w * 4 + j) * DD + colx];
      __syncthreads();
#pragma unroll 16
      for (int kk = 0; kk < 64; ++kk) {
        float wvk = Ws[kk][ln];
        float4 x = *(const float4*)&Xs[kk][w * 4];   // wave-broadcast read
        acc[0] = fmaf(x.x, wvk, acc[0]); acc[1] = fmaf(x.y, wvk, acc[1]);
        acc[2] = fmaf(x.z, wvk, acc[2]); acc[3] = fmaf(x.w, wvk, acc[3]);
      }
      __syncthreads();
    }
#pragma unroll
    for (int i = 0; i < 4; ++i) zxbuf[w * 4 + i][ln] = acc[i] + biasv;
    __syncthreads();

    // ========== Phase B: recurrence (1 barrier/step, overlapped) ==========
#pragma unroll 1
    for (int tl = 0; tl < CH; ++tl) {
      const int t = c * CH + tl;
      const float* rbuf = hbuf[t & 1];

      // x-part: lane ln<4 holds piece ln's zx value for column w.
      float zxv = (ln < 4) ? zxbuf[tl][ln * 16 + w] : 0.f;
      float a0 = (ln == 0) ? zxv : 0.f;
      float a1 = (ln == 1) ? zxv : 0.f;
      float a2 = (ln == 2) ? zxv : 0.f;
      float a3 = (ln == 3) ? zxv : 0.f;

      // Spin until group g of h(t-1) has landed (ready[g] set by pollers in
      // step t-1; monotonic, init -1 so t=0 never spins). Bounded.
#define WAITG(g) do {                                                       \
      int gd_ = 0;                                                          \
      while (__hip_atomic_load(&ready[g], __ATOMIC_ACQUIRE,                 \
                               __HIP_MEMORY_SCOPE_WORKGROUP) < t - 1) {     \
        if (++gd_ > GUARD_LIM) break;                                       \
      }                                                                     \
    } while (0)

#define DOTG(g, WA, WB, WC, WD) do { \
      float4 h4 = *(const float4*)&rbuf[(g) * 256 + ln * 4]; \
      a0 = fmaf(h4.x, WA.x, a0); a0 = fmaf(h4.y, WA.y, a0); \
      a0 = fmaf(h4.z, WA.z, a0); a0 = fmaf(h4.w, WA.w, a0); \
      a1 = fmaf(h4.x, WB.x, a1); a1 = fmaf(h4.y, WB.y, a1); \
      a1 = fmaf(h4.z, WB.z, a1); a1 = fmaf(h4.w, WB.w, a1); \
      a2 = fmaf(h4.x, WC.x, a2); a2 = fmaf(h4.y, WC.y, a2); \
      a2 = fmaf(h4.z, WC.z, a2); a2 = fmaf(h4.w, WC.w, a2); \
      a3 = fmaf(h4.x, WD.x, a3); a3 = fmaf(h4.y, WD.y, a3); \
      a3 = fmaf(h4.z, WD.z, a3); a3 = fmaf(h4.w, WD.w, a3); \
    } while (0)
      WAITG(0); DOTG(0, wA0, wB0, wC0, wD0);
      WAITG(1); DOTG(1, wA1, wB1, wC1, wD1);
      WAITG(2); DOTG(2, wA2, wB2, wC2, wD2);
      WAITG(3); DOTG(3, wA3, wB3, wC3, wD3);
#undef DOTG
#undef WAITG

      a0 = wave_allreduce_add(a0);
      a1 = wave_allreduce_add(a1);
      a2 = wave_allreduce_add(a2);
      a3 = wave_allreduce_add(a3);

      float f1 = fast_tanh(a0);
      float f2 = fast_tanh(a1);
      float g  = 1.f / (1.f + __expf(a2 * dtv - a3));
      float h  = fmaf(g, f1 - f2, f2);

      // Deposit h + count (release orders the hq write before the add).
      if (ln == 0) {
        hq[w] = h;
        __hip_atomic_fetch_add(&hcnt, 1, __ATOMIC_RELEASE,
                               __HIP_MEMORY_SCOPE_WORKGROUP);
      }
      if (l == 3 && t == TT - 1 && ln == 0 && out_last) out_last[col] = h;

      // Publisher: wave 15 (non-poll) waits for all 16 deposits, then one
      // contiguous 64B sc1 message per replica (lanes 0..R-1).
      if (w == 15) {
        const int target = 16 * (t + 1);
        int gd = 0;
        while (__hip_atomic_load(&hcnt, __ATOMIC_ACQUIRE,
                                 __HIP_MEMORY_SCOPE_WORKGROUP) < target) {
          if (++gd > GUARD_LIM) break;
        }
        if (ln < R) {
          float* dst = HB + (size_t)(l * R + ln) * TT * DD +
                       (size_t)t * DD + grp * 16;
          float4 q0 = *(const float4*)&hq[0];
          float4 q1 = *(const float4*)&hq[4];
          float4 q2 = *(const float4*)&hq[8];
          float4 q3 = *(const float4*)&hq[12];
          agent_store16(dst + 0,  q0);
          agent_store16(dst + 4,  q1);
          agent_store16(dst + 8,  q2);
          agent_store16(dst + 12, q3);
        }
      }

      // Pollers: wave w (<4) fills h-group w of row t into hbuf[(t+1)&1]
      // (16B/lane, per-lane early-out, backoff), then flags ready[w]=t.
      if (t < TT - 1 && w < 4) {
        const float* src = &hread[(size_t)t * DD + w * 256 + ln * 4];
        float4 v = make_float4(0.f, 0.f, 0.f, 0.f);
        bool ok = false;
        int tries = 0;
        while (true) {
          if (!ok) {
            v = agent_load16(src);
            ok = nan_free4(v);
          }
          if (__all(ok)) break;
          if (++tries > 8) __builtin_amdgcn_s_sleep(1);
          if (tries > GUARD_LIM) break;
        }
        if (!ok) v = make_float4(0.f, 0.f, 0.f, 0.f);   // degrade, don't hang
        *(float4*)&hbuf[(t + 1) & 1][w * 256 + ln * 4] = v;
        if (ln == 0)
          __hip_atomic_store(&ready[w], t, __ATOMIC_RELEASE,
                             __HIP_MEMORY_SCOPE_WORKGROUP);
      }
      __syncthreads();
    }
  }

  // Opaque guard: keeps lds_pad (and its store) from being DCE'd. Never true.
  if ((uintptr_t)out_last == 1) out_last[0] = lds_pad[tid & 1023];
}

extern "C" void kernel_launch(void* const* d_in, const int* in_sizes, int n_in,
                              void* d_out, int out_size, void* d_ws, size_t ws_size,
                              hipStream_t stream) {
  const float* sp  = (const float*)d_in[0];
  const float* rn  = (const float*)d_in[1];
  const float* dt  = (const float*)d_in[2];
  const float* rw  = (const float*)d_in[3];
  const float* rb  = (const float*)d_in[4];
  const float* Wf1 = (const float*)d_in[5];
  const float* bf1 = (const float*)d_in[6];
  const float* Wf2 = (const float*)d_in[7];
  const float* bf2 = (const float*)d_in[8];
  const float* Wta = (const float*)d_in[9];
  const float* bta = (const float*)d_in[10];
  const float* Wtb = (const float*)d_in[11];
  const float* btb = (const float*)d_in[12];

  float* ws = (float*)d_ws;
  float* X0 = ws;                         // [TT, DD]
  float* HB = ws + (size_t)TT * DD;       // [NL*R][TT, DD]
  float* out = (float*)d_out;
  const size_t seqB = sizeof(float) * (size_t)TT * DD;      // 8 MB

  // Adaptive replica count (power of 2, max 8), limited by workspace size.
  int R = 1;
  for (int cand = 8; cand >= 1; cand >>= 1) {
    size_t need = seqB * (size_t)(1 + NL * cand);
    if (need <= ws_size) { R = cand; break; }
  }

  // NaN-prefill all h buffers (poll protocol), then launch.
  (void)hipMemsetAsync(HB, 0xFF, (size_t)NL * R * seqB, stream);
  prep_kernel<<<(TT * DD) / 1024, 1024, 0, stream>>>(sp, rn, rw, rb, X0);
  persist_kernel<<<PBLK, NTHR, 0, stream>>>(X0, HB, R, Wf1, Wf2, Wta, Wtb,
      bf1, bf2, bta, btb, dt, out);
}